// Round 7
// baseline (121.731 us; speedup 1.0000x reference)
//
#include <hip/hip_runtime.h>

// BitConv2d: x (16,32,224,224) f32, w (32,32,3,3) f32, out (16,32,224,224) f32.
// out = conv(x_q, w_q) * (x_scale/127 * w_scale); x_q in [-128,127], w_q in {-1,0,1}.
// Both exact in bf16 -> bf16 MFMA computes the integer conv exactly (|sum| < 2^24).
//
// 2 dispatches: absmax (2049 blocks: 2048 x-slices + 1 weight-quant block),
// conv (784 blocks, each reduces the 2048 slot maxima then does 2 16x32 tiles).

typedef __attribute__((ext_vector_type(8))) short short8;
typedef __attribute__((ext_vector_type(4))) float f32x4;

#define HW    224
#define NCH   32
#define PLANE (HW * HW)   // 50176
#define TH 16
#define TW 32
// LDS tile: 612 pixels (18 rows x 34 cols) x 32 ch bf16 = 39168 B, granule-XOR swizzled.

__device__ __forceinline__ int lds_h(int pix, int c) {
    int sw = (pix & 3) ^ ((pix >> 2) & 3);
    return pix * 32 + (c & 7) + ((((c >> 3) ^ sw) & 3) << 3);
}

// ws layout: [0, 8192) = u32 slots[2048] (per-block maxima, fully rewritten each call);
// 8192: scal[0] = wscale; 8448: wbuf 18 frags x 512 bf16.
// frag (tap*2+kb): lane l elem j = w_q[kout = kb*16+(l&15)][c = (l>>4)*8+j][tap/3][tap%3]

__global__ __launch_bounds__(256) void absmax_kernel(const float* __restrict__ x,
                                                     const float* __restrict__ w,
                                                     unsigned* __restrict__ slots,
                                                     float* __restrict__ scal,
                                                     unsigned short* __restrict__ wbuf,
                                                     int n4)
{
    int tid = threadIdx.x;
    int lane = tid & 63, wv = tid >> 6;

    if (blockIdx.x == 2048) {
        // ---- weight block: wscale = mean|w|, quantize into MFMA B-frag layout ----
        float s = 0.f;
        for (int i = tid; i < 9216; i += 256) s += fabsf(w[i]);
        #pragma unroll
        for (int off = 32; off > 0; off >>= 1) s += __shfl_xor(s, off);
        __shared__ float sm[4];
        __shared__ float s_ws;
        if (lane == 0) sm[wv] = s;
        __syncthreads();
        if (tid == 0) {
            float wscale = (sm[0] + sm[1] + sm[2] + sm[3]) / 9216.f + 1e-5f;
            scal[0] = wscale;
            s_ws = wscale;
        }
        __syncthreads();
        float wscale = s_ws;
        for (int o = tid; o < 9216; o += 256) {
            int frag = o >> 9, rem = o & 511;
            int l = rem >> 3, j = rem & 7;
            int tap = frag >> 1, kb = frag & 1;
            int kout = kb * 16 + (l & 15);
            int c = ((l >> 4) << 3) + j;
            int r = tap / 3, ss = tap % 3;
            float wv2 = w[((kout * 32 + c) * 3 + r) * 3 + ss];
            float q = fminf(1.f, fmaxf(-1.f, rintf(wv2 / wscale)));   // round-half-even
            wbuf[o] = (unsigned short)(__float_as_uint(q) >> 16);     // exact bf16
        }
        return;
    }

    // ---- x-slice absmax ----
    const float4* x4 = (const float4*)x;
    float m = 0.f;
    for (int i = blockIdx.x * 256 + tid; i < n4; i += 2048 * 256) {
        float4 v = x4[i];
        m = fmaxf(m, fmaxf(fmaxf(fabsf(v.x), fabsf(v.y)),
                           fmaxf(fabsf(v.z), fabsf(v.w))));
    }
    #pragma unroll
    for (int off = 32; off > 0; off >>= 1)
        m = fmaxf(m, __shfl_xor(m, off));
    __shared__ float wm[4];
    if (lane == 0) wm[wv] = m;
    __syncthreads();
    if (tid == 0) {
        m = fmaxf(fmaxf(wm[0], wm[1]), fmaxf(wm[2], wm[3]));
        slots[blockIdx.x] = __float_as_uint(m);   // plain store, no atomics
    }
}

__global__ __launch_bounds__(512, 4) void conv_kernel(const float* __restrict__ x,
                                                      const unsigned short* __restrict__ wbuf,
                                                      const unsigned* __restrict__ slots,
                                                      const float* __restrict__ scal,
                                                      float* __restrict__ out)
{
    __shared__ __align__(16) unsigned short xs[612 * 32];
    __shared__ float sred[8];

    // bijective XCD swizzle: 784 blocks = 8 XCDs x 98 contiguous
    int bid = (blockIdx.x & 7) * 98 + (blockIdx.x >> 3);
    int tw = bid % 7;
    int rest = bid / 7;
    int qh = rest % 7;            // pair of vertically-adjacent tiles
    int n  = rest / 7;
    int w0 = tw * TW;

    int tid = threadIdx.x;
    int lane = tid & 63, wv = tid >> 6;

    const float* xn = x + n * (NCH * PLANE);
    float* on = out + n * (NCH * PLANE);
    const short8* wfp = (const short8*)wbuf;

    // staging thread map: slot = tid&7 (4-px col group), c = (tid>>3)&31, half = tid>>8
    int slot = tid & 7;
    int c = (tid >> 3) & 31;
    int half = tid >> 8;
    const float* tb = xn + c * PLANE + w0 + slot * 4;
    int pixb = 1 + slot * 4;
    int hbase = half * 9;

    // ---- issue tile-0 x loads (address-clamped; OOB masked at quantize time) ----
    int h0 = qh * 32;   // tile 0 row base
    float4 v[9];
    float hv[3];
    #pragma unroll
    for (int i = 0; i < 9; ++i) {
        int gh = h0 - 1 + hbase + i;
        int ghc = gh < 0 ? 0 : (gh > HW - 1 ? HW - 1 : gh);
        v[i] = *(const float4*)(tb + ghc * HW);
    }
    #pragma unroll
    for (int it = 0; it < 3; ++it) {
        int e = tid + it * 512;
        hv[it] = 0.f;
        if (e < 1152) {
            int side = e & 1, cc = (e >> 1) & 31, hp = e >> 6;
            int gh = h0 - 1 + hp;
            int gw = side ? (w0 + TW) : (w0 - 1);
            int ghc = gh < 0 ? 0 : (gh > HW - 1 ? HW - 1 : gh);
            int gwc = gw < 0 ? 0 : (gw > HW - 1 ? HW - 1 : gw);
            hv[it] = xn[cc * PLANE + ghc * HW + gwc];
        }
    }

    // ---- xmax from the 2048 slots (issued last; waits drain x loads too) ----
    uint4 sv = ((const uint4*)slots)[tid];
    float wscale = scal[0];
    float m2 = fmaxf(fmaxf(__uint_as_float(sv.x), __uint_as_float(sv.y)),
                     fmaxf(__uint_as_float(sv.z), __uint_as_float(sv.w)));
    #pragma unroll
    for (int off = 32; off > 0; off >>= 1)
        m2 = fmaxf(m2, __shfl_xor(m2, off));
    if (lane == 0) sred[wv] = m2;
    __syncthreads();
    float xmax = fmaxf(fmaxf(fmaxf(sred[0], sred[1]), fmaxf(sred[2], sred[3])),
                       fmaxf(fmaxf(sred[4], sred[5]), fmaxf(sred[6], sred[7])));
    float xscale = xmax + 1e-5f;
    float inv = 127.f / xscale;
    float osc = (xscale / 127.f) * wscale;

    int ln = lane & 15, cb = lane >> 4;

    #pragma unroll
    for (int t = 0; t < 2; ++t) {
        // ---- quantize + LDS writes (loads for this tile already in regs) ----
        #pragma unroll
        for (int i = 0; i < 9; ++i) {
            int gh = h0 - 1 + hbase + i;
            float vs = ((unsigned)gh < (unsigned)HW) ? inv : 0.f;
            int p0 = (hbase + i) * 34 + pixb;
            float q0 = rintf(fminf(127.f, fmaxf(-128.f, v[i].x * vs)));
            float q1 = rintf(fminf(127.f, fmaxf(-128.f, v[i].y * vs)));
            float q2 = rintf(fminf(127.f, fmaxf(-128.f, v[i].z * vs)));
            float q3 = rintf(fminf(127.f, fmaxf(-128.f, v[i].w * vs)));
            xs[lds_h(p0 + 0, c)] = (unsigned short)(__float_as_uint(q0) >> 16);
            xs[lds_h(p0 + 1, c)] = (unsigned short)(__float_as_uint(q1) >> 16);
            xs[lds_h(p0 + 2, c)] = (unsigned short)(__float_as_uint(q2) >> 16);
            xs[lds_h(p0 + 3, c)] = (unsigned short)(__float_as_uint(q3) >> 16);
        }
        #pragma unroll
        for (int it = 0; it < 3; ++it) {
            int e = tid + it * 512;
            if (e < 1152) {
                int side = e & 1, cc = (e >> 1) & 31, hp = e >> 6;
                int gh = h0 - 1 + hp;
                int gw = side ? (w0 + TW) : (w0 - 1);
                float vs = ((unsigned)gh < (unsigned)HW && (unsigned)gw < (unsigned)HW)
                               ? inv : 0.f;
                float q = rintf(fminf(127.f, fmaxf(-128.f, hv[it] * vs)));
                xs[lds_h(hp * 34 + (side ? 33 : 0), cc)] =
                    (unsigned short)(__float_as_uint(q) >> 16);
            }
        }
        __syncthreads();

        // ---- MFMA: 9 taps x [2 row][2 pixblock][2 kblock], one-ahead weight prefetch
        f32x4 acc[2][2][2] = {};
        short8 wa = wfp[lane];
        short8 wb = wfp[64 + lane];
        for (int tap = 0; tap < 9; ++tap) {
            short8 na, nb;
            if (tap < 8) {
                na = wfp[(2 * tap + 2) * 64 + lane];
                nb = wfp[(2 * tap + 3) * 64 + lane];
            }
            int r = tap / 3;
            int s2 = tap - r * 3;
            #pragma unroll
            for (int ri = 0; ri < 2; ++ri) {
                #pragma unroll
                for (int pb = 0; pb < 2; ++pb) {
                    int pix = (wv * 2 + ri + r) * 34 + pb * 16 + ln + s2;
                    int sw = (pix & 3) ^ ((pix >> 2) & 3);
                    const short8 a = *(const short8*)&xs[pix * 32 + (((cb ^ sw) & 3) << 3)];
                    acc[ri][pb][0] = __builtin_amdgcn_mfma_f32_16x16x32_bf16(
                        a, wa, acc[ri][pb][0], 0, 0, 0);
                    acc[ri][pb][1] = __builtin_amdgcn_mfma_f32_16x16x32_bf16(
                        a, wb, acc[ri][pb][1], 0, 0, 0);
                }
            }
            wa = na;
            wb = nb;
        }

        // ---- issue tile-1 x loads before the epilogue/barrier ----
        if (t == 0) {
            int h1 = h0 + TH;
            #pragma unroll
            for (int i = 0; i < 9; ++i) {
                int gh = h1 - 1 + hbase + i;
                int ghc = gh < 0 ? 0 : (gh > HW - 1 ? HW - 1 : gh);
                v[i] = *(const float4*)(tb + ghc * HW);
            }
            #pragma unroll
            for (int it = 0; it < 3; ++it) {
                int e = tid + it * 512;
                if (e < 1152) {
                    int side = e & 1, cc = (e >> 1) & 31, hp = e >> 6;
                    int gh = h1 - 1 + hp;
                    int gw = side ? (w0 + TW) : (w0 - 1);
                    int ghc = gh < 0 ? 0 : (gh > HW - 1 ? HW - 1 : gh);
                    int gwc = gw < 0 ? 0 : (gw > HW - 1 ? HW - 1 : gw);
                    hv[it] = xn[cc * PLANE + ghc * HW + gwc];
                }
            }
        }

        // ---- epilogue: D row = pixel -> lane holds 4 consecutive px: float4 stores
        #pragma unroll
        for (int ri = 0; ri < 2; ++ri) {
            int h = h0 + wv * 2 + ri;
            #pragma unroll
            for (int pb = 0; pb < 2; ++pb) {
                int wcol = w0 + pb * 16 + cb * 4;
                #pragma unroll
                for (int kb = 0; kb < 2; ++kb) {
                    int k = kb * 16 + ln;
                    f32x4 o;
                    o[0] = acc[ri][pb][kb][0] * osc;
                    o[1] = acc[ri][pb][kb][1] * osc;
                    o[2] = acc[ri][pb][kb][2] * osc;
                    o[3] = acc[ri][pb][kb][3] * osc;
                    *(f32x4*)&on[(k * HW + h) * HW + wcol] = o;
                }
            }
        }

        h0 += TH;
        if (t == 0) __syncthreads();   // LDS reuse guard (drains t1 loads + stores)
    }
}

extern "C" void kernel_launch(void* const* d_in, const int* in_sizes, int n_in,
                              void* d_out, int out_size, void* d_ws, size_t ws_size,
                              hipStream_t stream)
{
    const float* x = (const float*)d_in[0];
    const float* w = (const float*)d_in[1];
    float* outp = (float*)d_out;
    unsigned* slots = (unsigned*)d_ws;
    float* scal = (float*)((char*)d_ws + 8192);
    unsigned short* wbuf = (unsigned short*)((char*)d_ws + 8448);

    int n4 = (16 * NCH * PLANE) / 4;
    absmax_kernel<<<2049, 256, 0, stream>>>(x, w, slots, scal, wbuf, n4);
    conv_kernel<<<784, 512, 0, stream>>>(x, wbuf, slots, scal, outp);
}

// Round 8
// 83.183 us; speedup vs baseline: 1.4634x; 1.4634x over previous
//
#include <hip/hip_runtime.h>

// BitConv2d: x (16,32,224,224) f32, w (32,32,3,3) f32, out (16,32,224,224) f32.
// out = conv(x_q, w_q) * (x_scale/127 * w_scale); x_q in [-128,127], w_q in {-1,0,1}.
// Both exact in bf16 -> bf16 MFMA computes the integer conv exactly (|sum| < 2^24).
//
// 2 dispatches: absmax (2049 blocks: 2048 x-slices + 1 weight-quant block),
// conv (1568 blocks x one 16x32 tile; prologue reduces the 2048 slot maxima).

typedef __attribute__((ext_vector_type(8))) short short8;
typedef __attribute__((ext_vector_type(4))) float f32x4;

#define HW    224
#define NCH   32
#define PLANE (HW * HW)   // 50176
#define TH 16
#define TW 32
// LDS tile: 612 pixels (18 rows x 34 cols) x 32 ch bf16 = 39168 B, granule-XOR swizzled.

__device__ __forceinline__ int lds_h(int pix, int c) {
    int sw = (pix & 3) ^ ((pix >> 2) & 3);
    return pix * 32 + (c & 7) + ((((c >> 3) ^ sw) & 3) << 3);
}

__device__ __forceinline__ unsigned short q8(float v) {
    float q = rintf(fminf(127.f, fmaxf(-128.f, v)));   // round-half-even like jnp.round
    return (unsigned short)(__float_as_uint(q) >> 16); // exact bf16 of small ints
}

// ws layout: [0, 8192) = u32 slots[2048] (fully rewritten each call);
// 8192: scal[0] = wscale; 8448: wbuf 18 frags x 512 bf16.
// frag (tap*2+kb): lane l elem j = w_q[kout = kb*16+(l&15)][c = (l>>4)*8+j][tap/3][tap%3]

__global__ __launch_bounds__(256) void absmax_kernel(const float* __restrict__ x,
                                                     const float* __restrict__ w,
                                                     unsigned* __restrict__ slots,
                                                     float* __restrict__ scal,
                                                     unsigned short* __restrict__ wbuf,
                                                     int n4)
{
    int tid = threadIdx.x;
    int lane = tid & 63, wv = tid >> 6;

    if (blockIdx.x == 2048) {
        // ---- weight block: wscale = mean|w|, quantize into MFMA B-frag layout ----
        float s = 0.f;
        for (int i = tid; i < 9216; i += 256) s += fabsf(w[i]);
        #pragma unroll
        for (int off = 32; off > 0; off >>= 1) s += __shfl_xor(s, off);
        __shared__ float sm[4];
        __shared__ float s_ws;
        if (lane == 0) sm[wv] = s;
        __syncthreads();
        if (tid == 0) {
            float wscale = (sm[0] + sm[1] + sm[2] + sm[3]) / 9216.f + 1e-5f;
            scal[0] = wscale;
            s_ws = wscale;
        }
        __syncthreads();
        float wscale = s_ws;
        for (int o = tid; o < 9216; o += 256) {
            int frag = o >> 9, rem = o & 511;
            int l = rem >> 3, j = rem & 7;
            int tap = frag >> 1, kb = frag & 1;
            int kout = kb * 16 + (l & 15);
            int c = ((l >> 4) << 3) + j;
            int r = tap / 3, ss = tap % 3;
            float wv2 = w[((kout * 32 + c) * 3 + r) * 3 + ss];
            float q = fminf(1.f, fmaxf(-1.f, rintf(wv2 / wscale)));
            wbuf[o] = (unsigned short)(__float_as_uint(q) >> 16);   // exact bf16
        }
        return;
    }

    // ---- x-slice absmax ----
    const float4* x4 = (const float4*)x;
    float m = 0.f;
    for (int i = blockIdx.x * 256 + tid; i < n4; i += 2048 * 256) {
        float4 v = x4[i];
        m = fmaxf(m, fmaxf(fmaxf(fabsf(v.x), fabsf(v.y)),
                           fmaxf(fabsf(v.z), fabsf(v.w))));
    }
    #pragma unroll
    for (int off = 32; off > 0; off >>= 1)
        m = fmaxf(m, __shfl_xor(m, off));
    __shared__ float wm[4];
    if (lane == 0) wm[wv] = m;
    __syncthreads();
    if (tid == 0) {
        m = fmaxf(fmaxf(wm[0], wm[1]), fmaxf(wm[2], wm[3]));
        slots[blockIdx.x] = __float_as_uint(m);   // plain store, no atomics
    }
}

__global__ __launch_bounds__(512, 2) void conv_kernel(const float* __restrict__ x,
                                                      const unsigned short* __restrict__ wbuf,
                                                      const unsigned* __restrict__ slots,
                                                      const float* __restrict__ scal,
                                                      float* __restrict__ out)
{
    __shared__ __align__(16) unsigned short xs[612 * 32];
    __shared__ float sred[8];

    // bijective XCD swizzle: 1568 blocks = 8 XCDs x 196 contiguous
    int bid = (blockIdx.x & 7) * 196 + (blockIdx.x >> 3);
    int tw = bid % 7;
    int rest = bid / 7;
    int th = rest % 14;
    int n  = rest / 14;
    int h0 = th * TH, w0 = tw * TW;

    int tid = threadIdx.x;
    int lane = tid & 63, wv = tid >> 6;

    const float* xn = x + n * (NCH * PLANE);

    // staging map: slot = tid&7 (4-px col group), c = (tid>>3)&31, half = tid>>8
    int slot = tid & 7;
    int c = (tid >> 3) & 31;
    int hbase = (tid >> 8) * 9;
    const float* tb = xn + c * PLANE + w0 + slot * 4;
    int pixb = 1 + slot * 4;

    // ---- issue order: slots first (reduce waits only on this), then all x loads ----
    uint4 sv = ((const uint4*)slots)[tid];
    float wscale = scal[0];

    float hv[3];
    #pragma unroll
    for (int it = 0; it < 3; ++it) {
        int e = tid + it * 512;
        hv[it] = 0.f;
        if (e < 1152) {
            int side = e & 1, cc = (e >> 1) & 31, hp = e >> 6;
            int gh = h0 - 1 + hp;
            int gw = side ? (w0 + TW) : (w0 - 1);
            int ghc = gh < 0 ? 0 : (gh > HW - 1 ? HW - 1 : gh);
            int gwc = gw < 0 ? 0 : (gw > HW - 1 ? HW - 1 : gw);
            hv[it] = xn[cc * PLANE + ghc * HW + gwc];
        }
    }
    float4 va[5], vb[4];
    #pragma unroll
    for (int i = 0; i < 5; ++i) {
        int gh = h0 - 1 + hbase + i;
        int ghc = gh < 0 ? 0 : (gh > HW - 1 ? HW - 1 : gh);
        va[i] = *(const float4*)(tb + ghc * HW);
    }
    #pragma unroll
    for (int i = 0; i < 4; ++i) {
        int gh = h0 + 4 + hbase + i;      // rows hbase+5..hbase+8, gh = h0-1+hbase+5+i
        int ghc = gh < 0 ? 0 : (gh > HW - 1 ? HW - 1 : gh);
        vb[i] = *(const float4*)(tb + ghc * HW);
    }

    // ---- xmax reduce (x loads still in flight) ----
    float m2 = fmaxf(fmaxf(__uint_as_float(sv.x), __uint_as_float(sv.y)),
                     fmaxf(__uint_as_float(sv.z), __uint_as_float(sv.w)));
    #pragma unroll
    for (int off = 32; off > 0; off >>= 1)
        m2 = fmaxf(m2, __shfl_xor(m2, off));
    if (lane == 0) sred[wv] = m2;
    __syncthreads();
    float xmax = fmaxf(fmaxf(fmaxf(sred[0], sred[1]), fmaxf(sred[2], sred[3])),
                       fmaxf(fmaxf(sred[4], sred[5]), fmaxf(sred[6], sred[7])));
    float xscale = xmax + 1e-5f;
    float inv = 127.f / xscale;
    float osc = (xscale / 127.f) * wscale;

    // ---- quantize + LDS writes, batch A then halo then batch B (progressive drain) ----
    #pragma unroll
    for (int i = 0; i < 5; ++i) {
        int gh = h0 - 1 + hbase + i;
        float vs = ((unsigned)gh < (unsigned)HW) ? inv : 0.f;
        int p0 = (hbase + i) * 34 + pixb;
        xs[lds_h(p0 + 0, c)] = q8(va[i].x * vs);
        xs[lds_h(p0 + 1, c)] = q8(va[i].y * vs);
        xs[lds_h(p0 + 2, c)] = q8(va[i].z * vs);
        xs[lds_h(p0 + 3, c)] = q8(va[i].w * vs);
    }
    #pragma unroll
    for (int it = 0; it < 3; ++it) {
        int e = tid + it * 512;
        if (e < 1152) {
            int side = e & 1, cc = (e >> 1) & 31, hp = e >> 6;
            int gh = h0 - 1 + hp;
            int gw = side ? (w0 + TW) : (w0 - 1);
            float vs = ((unsigned)gh < (unsigned)HW && (unsigned)gw < (unsigned)HW)
                           ? inv : 0.f;
            xs[lds_h(hp * 34 + (side ? 33 : 0), cc)] = q8(hv[it] * vs);
        }
    }
    #pragma unroll
    for (int i = 0; i < 4; ++i) {
        int gh = h0 + 4 + hbase + i;
        float vs = ((unsigned)gh < (unsigned)HW) ? inv : 0.f;
        int p0 = (hbase + 5 + i) * 34 + pixb;
        xs[lds_h(p0 + 0, c)] = q8(vb[i].x * vs);
        xs[lds_h(p0 + 1, c)] = q8(vb[i].y * vs);
        xs[lds_h(p0 + 2, c)] = q8(vb[i].z * vs);
        xs[lds_h(p0 + 3, c)] = q8(vb[i].w * vs);
    }
    __syncthreads();

    // ---- MFMA: 9 taps x [2 row][2 pixblock][2 kblock], one-ahead weight prefetch ----
    int ln = lane & 15, cb = lane >> 4;
    f32x4 acc[2][2][2] = {};
    const short8* wfp = (const short8*)wbuf;
    short8 wa = wfp[lane];
    short8 wb = wfp[64 + lane];
    for (int tap = 0; tap < 9; ++tap) {
        short8 na, nb;
        if (tap < 8) {
            na = wfp[(2 * tap + 2) * 64 + lane];
            nb = wfp[(2 * tap + 3) * 64 + lane];
        }
        int r = tap / 3;
        int s2 = tap - r * 3;
        #pragma unroll
        for (int ri = 0; ri < 2; ++ri) {
            #pragma unroll
            for (int pb = 0; pb < 2; ++pb) {
                int pix = (wv * 2 + ri + r) * 34 + pb * 16 + ln + s2;
                int sw = (pix & 3) ^ ((pix >> 2) & 3);
                const short8 a = *(const short8*)&xs[pix * 32 + (((cb ^ sw) & 3) << 3)];
                acc[ri][pb][0] = __builtin_amdgcn_mfma_f32_16x16x32_bf16(
                    a, wa, acc[ri][pb][0], 0, 0, 0);
                acc[ri][pb][1] = __builtin_amdgcn_mfma_f32_16x16x32_bf16(
                    a, wb, acc[ri][pb][1], 0, 0, 0);
            }
        }
        wa = na;
        wb = nb;
    }

    // ---- epilogue: D row = pixel -> lane holds 4 consecutive px: float4 stores ----
    float* on = out + n * (NCH * PLANE);
    #pragma unroll
    for (int ri = 0; ri < 2; ++ri) {
        int h = h0 + wv * 2 + ri;
        #pragma unroll
        for (int pb = 0; pb < 2; ++pb) {
            int wcol = w0 + pb * 16 + cb * 4;
            #pragma unroll
            for (int kb = 0; kb < 2; ++kb) {
                int k = kb * 16 + ln;
                f32x4 o;
                o[0] = acc[ri][pb][kb][0] * osc;
                o[1] = acc[ri][pb][kb][1] * osc;
                o[2] = acc[ri][pb][kb][2] * osc;
                o[3] = acc[ri][pb][kb][3] * osc;
                *(f32x4*)&on[(k * HW + h) * HW + wcol] = o;
            }
        }
    }
}

extern "C" void kernel_launch(void* const* d_in, const int* in_sizes, int n_in,
                              void* d_out, int out_size, void* d_ws, size_t ws_size,
                              hipStream_t stream)
{
    const float* x = (const float*)d_in[0];
    const float* w = (const float*)d_in[1];
    float* outp = (float*)d_out;
    unsigned* slots = (unsigned*)d_ws;
    float* scal = (float*)((char*)d_ws + 8192);
    unsigned short* wbuf = (unsigned short*)((char*)d_ws + 8448);

    int n4 = (16 * NCH * PLANE) / 4;
    absmax_kernel<<<2049, 256, 0, stream>>>(x, w, slots, scal, wbuf, n4);
    conv_kernel<<<16 * 14 * 7, 512, 0, stream>>>(x, wbuf, slots, scal, outp);
}